// Round 14
// baseline (209.920 us; speedup 1.0000x reference)
//
#include <hip/hip_runtime.h>
#include <hip/hip_bf16.h>
#include <math.h>

#define N_ATOMS 8192
#define B_BATCH 64
#define E_EDGES 262144
#define S_SPEC 4
#define NMAX 8
#define PS_DIM 4096
#define H1_DIM 1024
#define CAP4 48
#define CUTR 5.0f
#define PI_F 3.14159265358979f

typedef __bf16 bf16;
typedef bf16 bf16x8 __attribute__((ext_vector_type(8)));
typedef float floatx4 __attribute__((ext_vector_type(4)));
typedef int intx8 __attribute__((ext_vector_type(8)));
typedef unsigned char u8;

// async global->LDS, 16B per lane; LDS dest = wave-uniform base + lane*16
__device__ __forceinline__ void g2lds16(const void* g, void* l) {
    __builtin_amdgcn_global_load_lds(
        (const __attribute__((address_space(1))) void*)g,
        (__attribute__((address_space(3))) void*)l, 16, 0, 0);
}

__device__ __forceinline__ int pk_fp8x4(float a, float b, float c, float d) {
    int lo = __builtin_amdgcn_cvt_pk_fp8_f32(a, b, 0, false);
    return __builtin_amdgcn_cvt_pk_fp8_f32(c, d, lo, true);
}

// ---------------------------------------------------------------- scatter
// Species-partitioned fixed-capacity buckets: bucket[(i*4+sp)*CAP4 + slot].
__global__ __launch_bounds__(256) void scatter_kernel(
    const float* __restrict__ pos, const float* __restrict__ cells,
    const int* __restrict__ numbers, const int* __restrict__ ei,
    const float* __restrict__ eo, const int* __restrict__ batch,
    int* __restrict__ cnt, float4* __restrict__ bucket)
{
    int e = blockIdx.x * 256 + threadIdx.x;
    int i = ei[e];
    int j = ei[E_EDGES + e];
    int b = batch[i];
    const float* cell = cells + b * 9;
    float o0 = eo[e * 3 + 0], o1 = eo[e * 3 + 1], o2 = eo[e * 3 + 2];
    float rv[3];
    #pragma unroll
    for (int d = 0; d < 3; ++d) {
        float shift = o0 * cell[0 * 3 + d] + o1 * cell[1 * 3 + d] + o2 * cell[2 * 3 + d];
        rv[d] = pos[j * 3 + d] - pos[i * 3 + d] + shift;
    }
    float r2 = rv[0] * rv[0] + rv[1] * rv[1] + rv[2] * rv[2] + 1e-12f;
    if (r2 >= CUTR * CUTR) return;   // fc == 0 -> zero contribution
    float r = sqrtf(r2);
    float a1 = r * (PI_F / CUTR);
    int sp = numbers[j];
    int q = i * S_SPEC + sp;
    int slot = atomicAdd(&cnt[q], 1);
    if (slot < CAP4)
        bucket[q * CAP4 + slot] = make_float4(rv[0], rv[1], rv[2], a1);
}

// ------------------------------------------------- fp32 -> fp8 transposes (both weights)
__global__ __launch_bounds__(256) void transpose_convert2(
    const float* __restrict__ W1, u8* __restrict__ Wt1,
    const float* __restrict__ W2, u8* __restrict__ Wt2)
{
    const float* W; u8* Wt; int K; float scale; int bx;
    if (blockIdx.x < 128) { W = W1; Wt = Wt1; K = PS_DIM; scale = 64.0f; bx = blockIdx.x; }
    else                  { W = W2; Wt = Wt2; K = H1_DIM; scale = 32.0f; bx = blockIdx.x - 128; }
    const int Nc = H1_DIM;
    __shared__ float t[32][33];
    int k0 = bx * 32, n0 = blockIdx.y * 32;
    int tx = threadIdx.x & 31, ty = threadIdx.x >> 5;  // ty in [0,8)
    #pragma unroll
    for (int r = 0; r < 32; r += 8)
        t[ty + r][tx] = W[(size_t)(k0 + ty + r) * Nc + n0 + tx];
    __syncthreads();
    if (threadIdx.x < 64) {
        int nl = threadIdx.x >> 1, cc = threadIdx.x & 1;
        int n = n0 + nl;
        unsigned int w[4];
        #pragma unroll
        for (int g = 0; g < 4; ++g) {
            int kb = cc * 16 + g * 4;
            w[g] = (unsigned int)pk_fp8x4(
                t[kb + 0][nl] * scale, t[kb + 1][nl] * scale,
                t[kb + 2][nl] * scale, t[kb + 3][nl] * scale);
        }
        int gc = (k0 >> 4) + cc;                        // global 16B-chunk index
        int gcs = (gc & ~7) | ((gc & 7) ^ (n & 7));     // swizzled
        *(uint4*)(Wt + (size_t)n * K + (size_t)gcs * 16) = make_uint4(w[0], w[1], w[2], w[3]);
    }
}

// ---------------------------------------------------------------- fused accum + PS/LN
__global__ __launch_bounds__(256) void accum_ps_kernel(
    const float4* __restrict__ bucket, const int* __restrict__ cnt,
    const float* __restrict__ gamma, const float* __restrict__ beta,
    const float* __restrict__ Wps, u8* __restrict__ psn, float* __restrict__ psl)
{
    __shared__ __align__(16) float cl[4][32 * 20];   // [atom][x*20+m], ld=20
    __shared__ __align__(16) u8 ps_s8[PS_DIM];
    __shared__ float red[8];
    __shared__ float red2[4];

    int t = threadIdx.x;
    int wv = t >> 6, lane = t & 63;
    int atom0 = blockIdx.x * 4;

    // ---------------- Phase A ----------------
    {
        int atom = atom0 + wv;
        int sp_l = lane >> 4;
        int nidx = (lane >> 1) & 7;
        float nf = (float)(nidx + 1);
        int par = lane & 1;

        int myCnt = cnt[atom * S_SPEC + sp_l];
        if (myCnt > CAP4) myCnt = CAP4;
        int m1 = max(myCnt, __shfl_xor(myCnt, 16));
        int mx = max(m1, __shfl_xor(m1, 32));

        const float4* q = bucket + (size_t)(atom * S_SPEC + sp_l) * CAP4;
        float acc[8] = {};
        #pragma unroll 2
        for (int e = 0; e < mx; ++e) {
            float4 d = q[e];
            bool valid = e < myCnt;
            float a1 = d.w;
            float inv_r = (PI_F / CUTR) * __frcp_rn(a1);
            float fc = 0.5f * __cosf(a1) + 0.5f;
            float rn = fc * inv_r * __sinf(nf * a1);
            rn = valid ? rn : 0.0f;

            float x = d.x * inv_r, y = d.y * inv_r, z = d.z * inv_r;
            float x2 = x * x, y2 = y * y, z2 = z * z;
            float Ys[8];
            if (par == 0) {
                Ys[0] = 0.28209479f;
                Ys[1] = 0.48860251f * y;
                Ys[2] = 0.48860251f * z;
                Ys[3] = 0.48860251f * x;
                Ys[4] = 1.09254843f * x * y;
                Ys[5] = 1.09254843f * y * z;
                Ys[6] = 0.31539157f * (3.0f * z2 - 1.0f);
                Ys[7] = 1.09254843f * x * z;
            } else {
                Ys[0] = 0.54627422f * (x2 - y2);
                Ys[1] = 0.59004359f * y * (3.0f * x2 - y2);
                Ys[2] = 2.89061144f * x * y * z;
                Ys[3] = 0.45704579f * y * (5.0f * z2 - 1.0f);
                Ys[4] = 0.37317633f * z * (5.0f * z2 - 3.0f);
                Ys[5] = 0.45704579f * x * (5.0f * z2 - 1.0f);
                Ys[6] = 1.44530572f * z * (x2 - y2);
                Ys[7] = 0.59004359f * x * (x2 - 3.0f * y2);
            }
            #pragma unroll
            for (int k = 0; k < 8; ++k) acc[k] += rn * Ys[k];
        }
        int X = sp_l * 8 + nidx;
        float* dst = &cl[wv][X * 20 + par * 8];
        *(float4*)(dst + 0) = make_float4(acc[0], acc[1], acc[2], acc[3]);
        *(float4*)(dst + 4) = make_float4(acc[4], acc[5], acc[6], acc[7]);
    }
    __syncthreads();

    // ---------------- Phase B ----------------
    for (int a = 0; a < 4; ++a) {
        int atom = atom0 + a;
        const float* cl_x = cl[a];

        int y = t & 31;
        int xb = t >> 5;
        float4 cya = *(const float4*)&cl_x[y * 20 + 0];
        float4 cyb = *(const float4*)&cl_x[y * 20 + 4];
        float4 cyc = *(const float4*)&cl_x[y * 20 + 8];
        float4 cyd = *(const float4*)&cl_x[y * 20 + 12];

        float ps[4][4];
        float sum = 0.0f, sumsq = 0.0f;
        #pragma unroll
        for (int q = 0; q < 4; ++q) {
            int x = xb + 8 * q;
            float4 xa = *(const float4*)&cl_x[x * 20 + 0];
            float4 xbv = *(const float4*)&cl_x[x * 20 + 4];
            float4 xc = *(const float4*)&cl_x[x * 20 + 8];
            float4 xd = *(const float4*)&cl_x[x * 20 + 12];
            float s0 = xa.x * cya.x;
            float s1 = xa.y * cya.y + xa.z * cya.z + xa.w * cya.w;
            float s2 = xbv.x * cyb.x + xbv.y * cyb.y + xbv.z * cyb.z + xbv.w * cyb.w
                     + xc.x * cyc.x;
            float s3 = xc.y * cyc.y + xc.z * cyc.z + xc.w * cyc.w
                     + xd.x * cyd.x + xd.y * cyd.y + xd.z * cyd.z + xd.w * cyd.w;
            ps[q][0] = s0; ps[q][1] = s1; ps[q][2] = s2; ps[q][3] = s3;
            sum += s0 + s1 + s2 + s3;
            sumsq += s0 * s0 + s1 * s1 + s2 * s2 + s3 * s3;
        }
        #pragma unroll
        for (int o = 32; o > 0; o >>= 1) {
            sum += __shfl_down(sum, o);
            sumsq += __shfl_down(sumsq, o);
        }
        if ((t & 63) == 0) { red[wv] = sum; red[4 + wv] = sumsq; }
        __syncthreads();
        float tot = red[0] + red[1] + red[2] + red[3];
        float totsq = red[4] + red[5] + red[6] + red[7];
        float mu = tot * (1.0f / PS_DIM);
        float var = totsq * (1.0f / PS_DIM) - mu * mu;
        float inv = rsqrtf(var + 1e-5f);

        float pacc = 0.0f;
        #pragma unroll
        for (int q = 0; q < 4; ++q) {
            int p = t + 256 * q;
            float4 g = *(const float4*)(gamma + p * 4);
            float4 bt = *(const float4*)(beta + p * 4);
            float4 w = *(const float4*)(Wps + p * 4);
            float v0 = (ps[q][0] - mu) * inv * g.x + bt.x;
            float v1 = (ps[q][1] - mu) * inv * g.y + bt.y;
            float v2 = (ps[q][2] - mu) * inv * g.z + bt.z;
            float v3 = (ps[q][3] - mu) * inv * g.w + bt.w;
            pacc += v0 * w.x + v1 * w.y + v2 * w.z + v3 * w.w;
            ((int*)ps_s8)[p] = pk_fp8x4(v0, v1, v2, v3);
        }
        __syncthreads();
        u8* rowp = psn + (size_t)atom * PS_DIM;
        int key = atom & 7;
        int gcs = (t & ~7) | ((t & 7) ^ key);
        *(uint4*)(rowp + (size_t)gcs * 16) = *(const uint4*)(ps_s8 + (size_t)t * 16);

        #pragma unroll
        for (int o = 32; o > 0; o >>= 1) pacc += __shfl_down(pacc, o);
        if ((t & 63) == 0) red2[wv] = pacc;
        __syncthreads();
        if (t == 0) psl[atom] = red2[0] + red2[1] + red2[2] + red2[3];
    }
}

// ------------------------------------------------- MX-fp8 MFMA GEMM1: h1 = fp8(silu(invs*psn@Wt1^T))
// 128x128 block tile (64x64 per wave, 4x4 frags), BK=128, LDS 32KB, grid 512.
// Frag-read traffic per output element is 2/3 of the 64x128 tile (LDS-read-bound
// kernel per R13 accounting). A, Bt fp8 chunk-swizzled; staged via global_load_lds.
__global__ __launch_bounds__(256) void gemm_f8_kernel(
    const u8* __restrict__ A, const u8* __restrict__ Bt,
    u8* __restrict__ H, int M, int Nc, int K, float invs)
{
    __shared__ __align__(16) char smem[32768];   // A: 128x128B = 16KB | B: 128x128B = 16KB
    int tid = threadIdx.x;
    int bm = blockIdx.x, bn = blockIdx.y;
    int wave = tid >> 6, lane = tid & 63;
    int wm = (wave >> 1) * 64, wn = (wave & 1) * 64;
    int lm = lane & 15, quad = lane >> 4;

    floatx4 acc[4][4] = {};
    const int rowA0 = bm * 128, rowB0 = bn * 128;
    const size_t stride = (size_t)K;
    const char* Ab = (const char*)A + (size_t)rowA0 * stride;
    const char* Bb = (const char*)Bt + (size_t)rowB0 * stride;
    const int sA = 0x7F7F7F7F, sB = 0x7F7F7F7F;

    for (int k0 = 0; k0 < K; k0 += 128) {
        #pragma unroll
        for (int s = 0; s < 4; ++s) {      // A: 1024 chunks
            int L = s * 256 + tid;
            int row = L >> 3, boff = (L & 7) * 16;
            int lbase = (s * 256 + wave * 64) * 16;
            g2lds16(Ab + (size_t)row * stride + k0 + boff, smem + lbase);
        }
        #pragma unroll
        for (int s = 0; s < 4; ++s) {      // B: 1024 chunks
            int L = s * 256 + tid;
            int row = L >> 3, boff = (L & 7) * 16;
            int lbase = (s * 256 + wave * 64) * 16;
            g2lds16(Bb + (size_t)row * stride + k0 + boff, smem + 16384 + lbase);
        }
        __syncthreads();
        int key = lm & 7;
        int c0 = (2 * quad) ^ key, c1 = (2 * quad + 1) ^ key;
        intx8 af[4], bfr[4];
        #pragma unroll
        for (int mi = 0; mi < 4; ++mi) {
            const char* base = smem + (wm + mi * 16 + lm) * 128;
            uint4 lo = *(const uint4*)(base + c0 * 16);
            uint4 hi = *(const uint4*)(base + c1 * 16);
            af[mi][0] = lo.x; af[mi][1] = lo.y; af[mi][2] = lo.z; af[mi][3] = lo.w;
            af[mi][4] = hi.x; af[mi][5] = hi.y; af[mi][6] = hi.z; af[mi][7] = hi.w;
        }
        #pragma unroll
        for (int ni = 0; ni < 4; ++ni) {
            const char* base = smem + 16384 + (wn + ni * 16 + lm) * 128;
            uint4 lo = *(const uint4*)(base + c0 * 16);
            uint4 hi = *(const uint4*)(base + c1 * 16);
            bfr[ni][0] = lo.x; bfr[ni][1] = lo.y; bfr[ni][2] = lo.z; bfr[ni][3] = lo.w;
            bfr[ni][4] = hi.x; bfr[ni][5] = hi.y; bfr[ni][6] = hi.z; bfr[ni][7] = hi.w;
        }
        #pragma unroll
        for (int mi = 0; mi < 4; ++mi)
            #pragma unroll
            for (int ni = 0; ni < 4; ++ni)
                acc[mi][ni] = __builtin_amdgcn_mfma_scale_f32_16x16x128_f8f6f4(
                    af[mi], bfr[ni], acc[mi][ni], 0, 0, 0, sA, 0, sB);
        __syncthreads();
    }

    u8* Cs8 = (u8*)smem;                 // 128 x 128 fp8 = 16KB
    #pragma unroll
    for (int mi = 0; mi < 4; ++mi)
        #pragma unroll
        for (int ni = 0; ni < 4; ++ni)
            #pragma unroll
            for (int r = 0; r < 4; ++r) {
                int row = wm + mi * 16 + quad * 4 + r;
                int col = wn + ni * 16 + lm;
                float v = acc[mi][ni][r] * invs;
                v = v / (1.0f + __expf(-v));
                int pk = __builtin_amdgcn_cvt_pk_fp8_f32(v, 0.0f, 0, false);
                Cs8[row * 128 + col] = (u8)(pk & 0xFF);
            }
    __syncthreads();
    #pragma unroll
    for (int c2 = 0; c2 < 4; ++c2) {
        int L = c2 * 256 + tid;          // 1024 chunks: row = L>>3, cc = L&7
        int row = L >> 3, cc = L & 7;
        int gcs = cc ^ (row & 7);        // rowA0 % 8 == 0, so local row&7 == global row&7
        *(uint4*)(H + (size_t)(rowA0 + row) * Nc + (size_t)(bn * 8 + gcs) * 16) =
            *(const uint4*)(Cs8 + (size_t)L * 16);
    }
}

// ------------------------------------------------- GEMM2 fused with W3 dot
// 64x128 tile (unchanged). All 64 rows belong to batch bm>>1; block-scalar
// plain store to nn_part[bm*8+bn]. h2 never touches HBM.
__global__ __launch_bounds__(256) void gemm2_fused_kernel(
    const u8* __restrict__ A, const u8* __restrict__ Bt,
    const float* __restrict__ W3, float* __restrict__ nn_part,
    int Nc, int K, float invs)
{
    __shared__ __align__(16) char smem[24576];
    int tid = threadIdx.x;
    int bm = blockIdx.x, bn = blockIdx.y;
    int wave = tid >> 6, lane = tid & 63;
    int wm = (wave >> 1) * 32, wn = (wave & 1) * 64;
    int lm = lane & 15, quad = lane >> 4;

    floatx4 acc[2][4] = {};
    const int rowA0 = bm * 64, rowB0 = bn * 128;
    const size_t stride = (size_t)K;
    const char* Ab = (const char*)A + (size_t)rowA0 * stride;
    const char* Bb = (const char*)Bt + (size_t)rowB0 * stride;
    const int sA = 0x7F7F7F7F, sB = 0x7F7F7F7F;

    for (int k0 = 0; k0 < K; k0 += 128) {
        #pragma unroll
        for (int s = 0; s < 2; ++s) {
            int L = s * 256 + tid;
            int row = L >> 3, boff = (L & 7) * 16;
            int lbase = (s * 256 + wave * 64) * 16;
            g2lds16(Ab + (size_t)row * stride + k0 + boff, smem + lbase);
        }
        #pragma unroll
        for (int s = 0; s < 4; ++s) {
            int L = s * 256 + tid;
            int row = L >> 3, boff = (L & 7) * 16;
            int lbase = (s * 256 + wave * 64) * 16;
            g2lds16(Bb + (size_t)row * stride + k0 + boff, smem + 8192 + lbase);
        }
        __syncthreads();
        int key = lm & 7;
        int c0 = (2 * quad) ^ key, c1 = (2 * quad + 1) ^ key;
        intx8 af[2], bfr[4];
        #pragma unroll
        for (int mi = 0; mi < 2; ++mi) {
            const char* base = smem + (wm + mi * 16 + lm) * 128;
            uint4 lo = *(const uint4*)(base + c0 * 16);
            uint4 hi = *(const uint4*)(base + c1 * 16);
            af[mi][0] = lo.x; af[mi][1] = lo.y; af[mi][2] = lo.z; af[mi][3] = lo.w;
            af[mi][4] = hi.x; af[mi][5] = hi.y; af[mi][6] = hi.z; af[mi][7] = hi.w;
        }
        #pragma unroll
        for (int ni = 0; ni < 4; ++ni) {
            const char* base = smem + 8192 + (wn + ni * 16 + lm) * 128;
            uint4 lo = *(const uint4*)(base + c0 * 16);
            uint4 hi = *(const uint4*)(base + c1 * 16);
            bfr[ni][0] = lo.x; bfr[ni][1] = lo.y; bfr[ni][2] = lo.z; bfr[ni][3] = lo.w;
            bfr[ni][4] = hi.x; bfr[ni][5] = hi.y; bfr[ni][6] = hi.z; bfr[ni][7] = hi.w;
        }
        #pragma unroll
        for (int mi = 0; mi < 2; ++mi)
            #pragma unroll
            for (int ni = 0; ni < 4; ++ni)
                acc[mi][ni] = __builtin_amdgcn_mfma_scale_f32_16x16x128_f8f6f4(
                    af[mi], bfr[ni], acc[mi][ni], 0, 0, 0, sA, 0, sB);
        __syncthreads();
    }

    float lt = 0.0f;
    #pragma unroll
    for (int ni = 0; ni < 4; ++ni) {
        float w3v = W3[bn * 128 + wn + ni * 16 + lm];
        #pragma unroll
        for (int mi = 0; mi < 2; ++mi)
            #pragma unroll
            for (int r = 0; r < 4; ++r) {
                float v = acc[mi][ni][r] * invs;
                v = v / (1.0f + __expf(-v));
                lt += v * w3v;
            }
    }
    #pragma unroll
    for (int o = 32; o > 0; o >>= 1) lt += __shfl_down(lt, o);
    float* wsum = (float*)smem;
    if (lane == 0) wsum[wave] = lt;
    __syncthreads();
    if (tid == 0)
        nn_part[bm * 8 + bn] = wsum[0] + wsum[1] + wsum[2] + wsum[3];
}

// ------------------------------------------------- finalize: tiny per-batch epilogue
__global__ __launch_bounds__(128) void finalize_kernel(
    const float* __restrict__ psl, const int* __restrict__ numbers,
    const float* __restrict__ nn_part, const float* __restrict__ Wcomp,
    float* __restrict__ out)
{
    int b = blockIdx.x, t = threadIdx.x;
    __shared__ float sh[2];
    __shared__ int cnt4[S_SPEC];
    if (t < S_SPEC) cnt4[t] = 0;
    __syncthreads();
    int a = b * 128 + t;
    float e = psl[a];
    if (t < 16) e += nn_part[b * 16 + t];
    atomicAdd(&cnt4[numbers[a]], 1);
    #pragma unroll
    for (int o = 32; o > 0; o >>= 1) e += __shfl_down(e, o);
    if ((t & 63) == 0) sh[t >> 6] = e;
    __syncthreads();
    if (t == 0) {
        float r = (sh[0] + sh[1]) * (1.0f / 128.0f);
        #pragma unroll
        for (int s = 0; s < S_SPEC; ++s) r += (float)cnt4[s] * Wcomp[s];
        out[b] = r;
    }
}

extern "C" void kernel_launch(void* const* d_in, const int* in_sizes, int n_in,
                              void* d_out, int out_size, void* d_ws, size_t ws_size,
                              hipStream_t stream)
{
    const float* positions = (const float*)d_in[0];
    const float* cells     = (const float*)d_in[1];
    const int*   numbers   = (const int*)d_in[2];
    const int*   ei        = (const int*)d_in[3];
    const float* eo        = (const float*)d_in[4];
    const int*   batch     = (const int*)d_in[5];
    const float* gamma     = (const float*)d_in[6];
    const float* beta      = (const float*)d_in[7];
    const float* W_ps      = (const float*)d_in[8];
    const float* W1        = (const float*)d_in[9];
    const float* W2        = (const float*)d_in[10];
    const float* W3        = (const float*)d_in[11];
    const float* W_comp    = (const float*)d_in[12];
    float* out = (float*)d_out;

    char* ws = (char*)d_ws;
    float4* bucket = (float4*)ws;  ws += (size_t)N_ATOMS * S_SPEC * CAP4 * 16;  // 25.2 MB
    u8*    psn  = (u8*)ws;     ws += (size_t)N_ATOMS * PS_DIM;             // 32 MB
    u8*    h1   = (u8*)ws;     ws += (size_t)N_ATOMS * H1_DIM;             // 8 MB
    u8*    Wt1  = (u8*)ws;     ws += (size_t)H1_DIM * PS_DIM;              // 4 MB
    u8*    Wt2  = (u8*)ws;     ws += (size_t)H1_DIM * H1_DIM;              // 1 MB
    float* psl  = (float*)ws;  ws += (size_t)N_ATOMS * 4;
    int*   cnt  = (int*)ws;    ws += (size_t)N_ATOMS * S_SPEC * 4;         // 128 KB
    float* nn_part = (float*)ws; ws += (size_t)1024 * 4;                   // 4 KB

    hipMemsetAsync(cnt, 0, N_ATOMS * S_SPEC * sizeof(int), stream);

    scatter_kernel<<<E_EDGES / 256, 256, 0, stream>>>(
        positions, cells, numbers, ei, eo, batch, cnt, bucket);

    transpose_convert2<<<dim3(160, 32), 256, 0, stream>>>(W1, Wt1, W2, Wt2);

    accum_ps_kernel<<<N_ATOMS / 4, 256, 0, stream>>>(
        bucket, cnt, gamma, beta, W_ps, psn, psl);

    gemm_f8_kernel<<<dim3(N_ATOMS / 128, H1_DIM / 128), 256, 0, stream>>>(
        psn, Wt1, h1, N_ATOMS, H1_DIM, PS_DIM, 1.0f / 64.0f);
    gemm2_fused_kernel<<<dim3(N_ATOMS / 64, H1_DIM / 128), 256, 0, stream>>>(
        h1, Wt2, W3, nn_part, H1_DIM, H1_DIM, 1.0f / 32.0f);

    finalize_kernel<<<B_BATCH, 128, 0, stream>>>(psl, numbers, nn_part, W_comp, out);
}

// Round 15
// 201.703 us; speedup vs baseline: 1.0407x; 1.0407x over previous
//
#include <hip/hip_runtime.h>
#include <hip/hip_bf16.h>
#include <math.h>

#define N_ATOMS 8192
#define B_BATCH 64
#define E_EDGES 262144
#define S_SPEC 4
#define NMAX 8
#define PS_DIM 4096
#define H1_DIM 1024
#define CAP4 48
#define CUTR 5.0f
#define PI_F 3.14159265358979f

typedef __bf16 bf16;
typedef bf16 bf16x8 __attribute__((ext_vector_type(8)));
typedef float floatx4 __attribute__((ext_vector_type(4)));
typedef int intx8 __attribute__((ext_vector_type(8)));
typedef unsigned char u8;

// async global->LDS, 16B per lane; LDS dest = wave-uniform base + lane*16
__device__ __forceinline__ void g2lds16(const void* g, void* l) {
    __builtin_amdgcn_global_load_lds(
        (const __attribute__((address_space(1))) void*)g,
        (__attribute__((address_space(3))) void*)l, 16, 0, 0);
}

__device__ __forceinline__ int pk_fp8x4(float a, float b, float c, float d) {
    int lo = __builtin_amdgcn_cvt_pk_fp8_f32(a, b, 0, false);
    return __builtin_amdgcn_cvt_pk_fp8_f32(c, d, lo, true);
}

// ---------------------------------------------------------------- scatter
__global__ __launch_bounds__(256) void scatter_kernel(
    const float* __restrict__ pos, const float* __restrict__ cells,
    const int* __restrict__ numbers, const int* __restrict__ ei,
    const float* __restrict__ eo, const int* __restrict__ batch,
    int* __restrict__ cnt, float4* __restrict__ bucket)
{
    int e = blockIdx.x * 256 + threadIdx.x;
    int i = ei[e];
    int j = ei[E_EDGES + e];
    int b = batch[i];
    const float* cell = cells + b * 9;
    float o0 = eo[e * 3 + 0], o1 = eo[e * 3 + 1], o2 = eo[e * 3 + 2];
    float rv[3];
    #pragma unroll
    for (int d = 0; d < 3; ++d) {
        float shift = o0 * cell[0 * 3 + d] + o1 * cell[1 * 3 + d] + o2 * cell[2 * 3 + d];
        rv[d] = pos[j * 3 + d] - pos[i * 3 + d] + shift;
    }
    float r2 = rv[0] * rv[0] + rv[1] * rv[1] + rv[2] * rv[2] + 1e-12f;
    if (r2 >= CUTR * CUTR) return;   // fc == 0 -> zero contribution
    float r = sqrtf(r2);
    float a1 = r * (PI_F / CUTR);
    int sp = numbers[j];
    int q = i * S_SPEC + sp;
    int slot = atomicAdd(&cnt[q], 1);
    if (slot < CAP4)
        bucket[q * CAP4 + slot] = make_float4(rv[0], rv[1], rv[2], a1);
}

// ------------------------------------------------- fp32 -> fp8 transposes (both weights)
__global__ __launch_bounds__(256) void transpose_convert2(
    const float* __restrict__ W1, u8* __restrict__ Wt1,
    const float* __restrict__ W2, u8* __restrict__ Wt2)
{
    const float* W; u8* Wt; int K; float scale; int bx;
    if (blockIdx.x < 128) { W = W1; Wt = Wt1; K = PS_DIM; scale = 64.0f; bx = blockIdx.x; }
    else                  { W = W2; Wt = Wt2; K = H1_DIM; scale = 32.0f; bx = blockIdx.x - 128; }
    const int Nc = H1_DIM;
    __shared__ float t[32][33];
    int k0 = bx * 32, n0 = blockIdx.y * 32;
    int tx = threadIdx.x & 31, ty = threadIdx.x >> 5;  // ty in [0,8)
    #pragma unroll
    for (int r = 0; r < 32; r += 8)
        t[ty + r][tx] = W[(size_t)(k0 + ty + r) * Nc + n0 + tx];
    __syncthreads();
    if (threadIdx.x < 64) {
        int nl = threadIdx.x >> 1, cc = threadIdx.x & 1;
        int n = n0 + nl;
        unsigned int w[4];
        #pragma unroll
        for (int g = 0; g < 4; ++g) {
            int kb = cc * 16 + g * 4;
            w[g] = (unsigned int)pk_fp8x4(
                t[kb + 0][nl] * scale, t[kb + 1][nl] * scale,
                t[kb + 2][nl] * scale, t[kb + 3][nl] * scale);
        }
        int gc = (k0 >> 4) + cc;                        // global 16B-chunk index
        int gcs = (gc & ~7) | ((gc & 7) ^ (n & 7));     // swizzled
        *(uint4*)(Wt + (size_t)n * K + (size_t)gcs * 16) = make_uint4(w[0], w[1], w[2], w[3]);
    }
}

// ---------------------------------------------------------------- fused accum + PS/LN
__global__ __launch_bounds__(256) void accum_ps_kernel(
    const float4* __restrict__ bucket, const int* __restrict__ cnt,
    const float* __restrict__ gamma, const float* __restrict__ beta,
    const float* __restrict__ Wps, u8* __restrict__ psn, float* __restrict__ psl)
{
    __shared__ __align__(16) float cl[4][32 * 20];   // [atom][x*20+m], ld=20
    __shared__ __align__(16) u8 ps_s8[PS_DIM];
    __shared__ float red[8];
    __shared__ float red2[4];

    int t = threadIdx.x;
    int wv = t >> 6, lane = t & 63;
    int atom0 = blockIdx.x * 4;

    // ---------------- Phase A ----------------
    {
        int atom = atom0 + wv;
        int sp_l = lane >> 4;
        int nidx = (lane >> 1) & 7;
        float nf = (float)(nidx + 1);
        int par = lane & 1;

        int myCnt = cnt[atom * S_SPEC + sp_l];
        if (myCnt > CAP4) myCnt = CAP4;
        int m1 = max(myCnt, __shfl_xor(myCnt, 16));
        int mx = max(m1, __shfl_xor(m1, 32));

        const float4* q = bucket + (size_t)(atom * S_SPEC + sp_l) * CAP4;
        float acc[8] = {};
        #pragma unroll 2
        for (int e = 0; e < mx; ++e) {
            float4 d = q[e];
            bool valid = e < myCnt;
            float a1 = d.w;
            float inv_r = (PI_F / CUTR) * __frcp_rn(a1);
            float fc = 0.5f * __cosf(a1) + 0.5f;
            float rn = fc * inv_r * __sinf(nf * a1);
            rn = valid ? rn : 0.0f;

            float x = d.x * inv_r, y = d.y * inv_r, z = d.z * inv_r;
            float x2 = x * x, y2 = y * y, z2 = z * z;
            float Ys[8];
            if (par == 0) {
                Ys[0] = 0.28209479f;
                Ys[1] = 0.48860251f * y;
                Ys[2] = 0.48860251f * z;
                Ys[3] = 0.48860251f * x;
                Ys[4] = 1.09254843f * x * y;
                Ys[5] = 1.09254843f * y * z;
                Ys[6] = 0.31539157f * (3.0f * z2 - 1.0f);
                Ys[7] = 1.09254843f * x * z;
            } else {
                Ys[0] = 0.54627422f * (x2 - y2);
                Ys[1] = 0.59004359f * y * (3.0f * x2 - y2);
                Ys[2] = 2.89061144f * x * y * z;
                Ys[3] = 0.45704579f * y * (5.0f * z2 - 1.0f);
                Ys[4] = 0.37317633f * z * (5.0f * z2 - 3.0f);
                Ys[5] = 0.45704579f * x * (5.0f * z2 - 1.0f);
                Ys[6] = 1.44530572f * z * (x2 - y2);
                Ys[7] = 0.59004359f * x * (x2 - 3.0f * y2);
            }
            #pragma unroll
            for (int k = 0; k < 8; ++k) acc[k] += rn * Ys[k];
        }
        int X = sp_l * 8 + nidx;
        float* dst = &cl[wv][X * 20 + par * 8];
        *(float4*)(dst + 0) = make_float4(acc[0], acc[1], acc[2], acc[3]);
        *(float4*)(dst + 4) = make_float4(acc[4], acc[5], acc[6], acc[7]);
    }
    __syncthreads();

    // ---------------- Phase B ----------------
    for (int a = 0; a < 4; ++a) {
        int atom = atom0 + a;
        const float* cl_x = cl[a];

        int y = t & 31;
        int xb = t >> 5;
        float4 cya = *(const float4*)&cl_x[y * 20 + 0];
        float4 cyb = *(const float4*)&cl_x[y * 20 + 4];
        float4 cyc = *(const float4*)&cl_x[y * 20 + 8];
        float4 cyd = *(const float4*)&cl_x[y * 20 + 12];

        float ps[4][4];
        float sum = 0.0f, sumsq = 0.0f;
        #pragma unroll
        for (int q = 0; q < 4; ++q) {
            int x = xb + 8 * q;
            float4 xa = *(const float4*)&cl_x[x * 20 + 0];
            float4 xbv = *(const float4*)&cl_x[x * 20 + 4];
            float4 xc = *(const float4*)&cl_x[x * 20 + 8];
            float4 xd = *(const float4*)&cl_x[x * 20 + 12];
            float s0 = xa.x * cya.x;
            float s1 = xa.y * cya.y + xa.z * cya.z + xa.w * cya.w;
            float s2 = xbv.x * cyb.x + xbv.y * cyb.y + xbv.z * cyb.z + xbv.w * cyb.w
                     + xc.x * cyc.x;
            float s3 = xc.y * cyc.y + xc.z * cyc.z + xc.w * cyc.w
                     + xd.x * cyd.x + xd.y * cyd.y + xd.z * cyd.z + xd.w * cyd.w;
            ps[q][0] = s0; ps[q][1] = s1; ps[q][2] = s2; ps[q][3] = s3;
            sum += s0 + s1 + s2 + s3;
            sumsq += s0 * s0 + s1 * s1 + s2 * s2 + s3 * s3;
        }
        #pragma unroll
        for (int o = 32; o > 0; o >>= 1) {
            sum += __shfl_down(sum, o);
            sumsq += __shfl_down(sumsq, o);
        }
        if ((t & 63) == 0) { red[wv] = sum; red[4 + wv] = sumsq; }
        __syncthreads();
        float tot = red[0] + red[1] + red[2] + red[3];
        float totsq = red[4] + red[5] + red[6] + red[7];
        float mu = tot * (1.0f / PS_DIM);
        float var = totsq * (1.0f / PS_DIM) - mu * mu;
        float inv = rsqrtf(var + 1e-5f);

        float pacc = 0.0f;
        #pragma unroll
        for (int q = 0; q < 4; ++q) {
            int p = t + 256 * q;
            float4 g = *(const float4*)(gamma + p * 4);
            float4 bt = *(const float4*)(beta + p * 4);
            float4 w = *(const float4*)(Wps + p * 4);
            float v0 = (ps[q][0] - mu) * inv * g.x + bt.x;
            float v1 = (ps[q][1] - mu) * inv * g.y + bt.y;
            float v2 = (ps[q][2] - mu) * inv * g.z + bt.z;
            float v3 = (ps[q][3] - mu) * inv * g.w + bt.w;
            pacc += v0 * w.x + v1 * w.y + v2 * w.z + v3 * w.w;
            ((int*)ps_s8)[p] = pk_fp8x4(v0, v1, v2, v3);
        }
        __syncthreads();
        u8* rowp = psn + (size_t)atom * PS_DIM;
        int key = atom & 7;
        int gcs = (t & ~7) | ((t & 7) ^ key);
        *(uint4*)(rowp + (size_t)gcs * 16) = *(const uint4*)(ps_s8 + (size_t)t * 16);

        #pragma unroll
        for (int o = 32; o > 0; o >>= 1) pacc += __shfl_down(pacc, o);
        if ((t & 63) == 0) red2[wv] = pacc;
        __syncthreads();
        if (t == 0) psl[atom] = red2[0] + red2[1] + red2[2] + red2[3];
    }
}

// ------------------------------------------------- MX-fp8 MFMA GEMM1: h1 = fp8(silu(invs*psn@Wt1^T))
// 128x128 block tile (64x64 per wave, 4x4 frags), BK=128, LDS 32KB, grid 512.
__global__ __launch_bounds__(256) void gemm_f8_kernel(
    const u8* __restrict__ A, const u8* __restrict__ Bt,
    u8* __restrict__ H, int M, int Nc, int K, float invs)
{
    __shared__ __align__(16) char smem[32768];   // A: 128x128B = 16KB | B: 128x128B = 16KB
    int tid = threadIdx.x;
    int bm = blockIdx.x, bn = blockIdx.y;
    int wave = tid >> 6, lane = tid & 63;
    int wm = (wave >> 1) * 64, wn = (wave & 1) * 64;
    int lm = lane & 15, quad = lane >> 4;

    floatx4 acc[4][4] = {};
    const int rowA0 = bm * 128, rowB0 = bn * 128;
    const size_t stride = (size_t)K;
    const char* Ab = (const char*)A + (size_t)rowA0 * stride;
    const char* Bb = (const char*)Bt + (size_t)rowB0 * stride;
    const int sA = 0x7F7F7F7F, sB = 0x7F7F7F7F;

    for (int k0 = 0; k0 < K; k0 += 128) {
        #pragma unroll
        for (int s = 0; s < 4; ++s) {      // A: 1024 chunks
            int L = s * 256 + tid;
            int row = L >> 3, boff = (L & 7) * 16;
            int lbase = (s * 256 + wave * 64) * 16;
            g2lds16(Ab + (size_t)row * stride + k0 + boff, smem + lbase);
        }
        #pragma unroll
        for (int s = 0; s < 4; ++s) {      // B: 1024 chunks
            int L = s * 256 + tid;
            int row = L >> 3, boff = (L & 7) * 16;
            int lbase = (s * 256 + wave * 64) * 16;
            g2lds16(Bb + (size_t)row * stride + k0 + boff, smem + 16384 + lbase);
        }
        __syncthreads();
        int key = lm & 7;
        int c0 = (2 * quad) ^ key, c1 = (2 * quad + 1) ^ key;
        intx8 af[4], bfr[4];
        #pragma unroll
        for (int mi = 0; mi < 4; ++mi) {
            const char* base = smem + (wm + mi * 16 + lm) * 128;
            uint4 lo = *(const uint4*)(base + c0 * 16);
            uint4 hi = *(const uint4*)(base + c1 * 16);
            af[mi][0] = lo.x; af[mi][1] = lo.y; af[mi][2] = lo.z; af[mi][3] = lo.w;
            af[mi][4] = hi.x; af[mi][5] = hi.y; af[mi][6] = hi.z; af[mi][7] = hi.w;
        }
        #pragma unroll
        for (int ni = 0; ni < 4; ++ni) {
            const char* base = smem + 16384 + (wn + ni * 16 + lm) * 128;
            uint4 lo = *(const uint4*)(base + c0 * 16);
            uint4 hi = *(const uint4*)(base + c1 * 16);
            bfr[ni][0] = lo.x; bfr[ni][1] = lo.y; bfr[ni][2] = lo.z; bfr[ni][3] = lo.w;
            bfr[ni][4] = hi.x; bfr[ni][5] = hi.y; bfr[ni][6] = hi.z; bfr[ni][7] = hi.w;
        }
        #pragma unroll
        for (int mi = 0; mi < 4; ++mi)
            #pragma unroll
            for (int ni = 0; ni < 4; ++ni)
                acc[mi][ni] = __builtin_amdgcn_mfma_scale_f32_16x16x128_f8f6f4(
                    af[mi], bfr[ni], acc[mi][ni], 0, 0, 0, sA, 0, sB);
        __syncthreads();
    }

    u8* Cs8 = (u8*)smem;                 // 128 x 128 fp8 = 16KB
    #pragma unroll
    for (int mi = 0; mi < 4; ++mi)
        #pragma unroll
        for (int ni = 0; ni < 4; ++ni)
            #pragma unroll
            for (int r = 0; r < 4; ++r) {
                int row = wm + mi * 16 + quad * 4 + r;
                int col = wn + ni * 16 + lm;
                float v = acc[mi][ni][r] * invs;
                v = v / (1.0f + __expf(-v));
                int pk = __builtin_amdgcn_cvt_pk_fp8_f32(v, 0.0f, 0, false);
                Cs8[row * 128 + col] = (u8)(pk & 0xFF);
            }
    __syncthreads();
    #pragma unroll
    for (int c2 = 0; c2 < 4; ++c2) {
        int L = c2 * 256 + tid;          // 1024 chunks: row = L>>3, cc = L&7
        int row = L >> 3, cc = L & 7;
        int gcs = cc ^ (row & 7);        // rowA0 % 8 == 0, so local row&7 == global row&7
        *(uint4*)(H + (size_t)(rowA0 + row) * Nc + (size_t)(bn * 8 + gcs) * 16) =
            *(const uint4*)(Cs8 + (size_t)L * 16);
    }
}

// ------------------------------------------------- GEMM2 fused with W3 dot
// 128x128 block tile (matches gemm1). All 128 rows of tile bm are batch bm;
// silu(invs*acc)·W3[col] reduces to one scalar per block -> plain store to
// nn_part[bm*8+bn] (512 uncontended slots). h2 never touches HBM.
__global__ __launch_bounds__(256) void gemm2_fused_kernel(
    const u8* __restrict__ A, const u8* __restrict__ Bt,
    const float* __restrict__ W3, float* __restrict__ nn_part,
    int Nc, int K, float invs)
{
    __shared__ __align__(16) char smem[32768];
    int tid = threadIdx.x;
    int bm = blockIdx.x, bn = blockIdx.y;
    int wave = tid >> 6, lane = tid & 63;
    int wm = (wave >> 1) * 64, wn = (wave & 1) * 64;
    int lm = lane & 15, quad = lane >> 4;

    floatx4 acc[4][4] = {};
    const int rowA0 = bm * 128, rowB0 = bn * 128;
    const size_t stride = (size_t)K;
    const char* Ab = (const char*)A + (size_t)rowA0 * stride;
    const char* Bb = (const char*)Bt + (size_t)rowB0 * stride;
    const int sA = 0x7F7F7F7F, sB = 0x7F7F7F7F;

    for (int k0 = 0; k0 < K; k0 += 128) {
        #pragma unroll
        for (int s = 0; s < 4; ++s) {      // A: 1024 chunks
            int L = s * 256 + tid;
            int row = L >> 3, boff = (L & 7) * 16;
            int lbase = (s * 256 + wave * 64) * 16;
            g2lds16(Ab + (size_t)row * stride + k0 + boff, smem + lbase);
        }
        #pragma unroll
        for (int s = 0; s < 4; ++s) {      // B: 1024 chunks
            int L = s * 256 + tid;
            int row = L >> 3, boff = (L & 7) * 16;
            int lbase = (s * 256 + wave * 64) * 16;
            g2lds16(Bb + (size_t)row * stride + k0 + boff, smem + 16384 + lbase);
        }
        __syncthreads();
        int key = lm & 7;
        int c0 = (2 * quad) ^ key, c1 = (2 * quad + 1) ^ key;
        intx8 af[4], bfr[4];
        #pragma unroll
        for (int mi = 0; mi < 4; ++mi) {
            const char* base = smem + (wm + mi * 16 + lm) * 128;
            uint4 lo = *(const uint4*)(base + c0 * 16);
            uint4 hi = *(const uint4*)(base + c1 * 16);
            af[mi][0] = lo.x; af[mi][1] = lo.y; af[mi][2] = lo.z; af[mi][3] = lo.w;
            af[mi][4] = hi.x; af[mi][5] = hi.y; af[mi][6] = hi.z; af[mi][7] = hi.w;
        }
        #pragma unroll
        for (int ni = 0; ni < 4; ++ni) {
            const char* base = smem + 16384 + (wn + ni * 16 + lm) * 128;
            uint4 lo = *(const uint4*)(base + c0 * 16);
            uint4 hi = *(const uint4*)(base + c1 * 16);
            bfr[ni][0] = lo.x; bfr[ni][1] = lo.y; bfr[ni][2] = lo.z; bfr[ni][3] = lo.w;
            bfr[ni][4] = hi.x; bfr[ni][5] = hi.y; bfr[ni][6] = hi.z; bfr[ni][7] = hi.w;
        }
        #pragma unroll
        for (int mi = 0; mi < 4; ++mi)
            #pragma unroll
            for (int ni = 0; ni < 4; ++ni)
                acc[mi][ni] = __builtin_amdgcn_mfma_scale_f32_16x16x128_f8f6f4(
                    af[mi], bfr[ni], acc[mi][ni], 0, 0, 0, sA, 0, sB);
        __syncthreads();
    }

    // Epilogue: lane-local dot with W3, wave reduce, LDS reduce, ONE plain store.
    float lt = 0.0f;
    #pragma unroll
    for (int ni = 0; ni < 4; ++ni) {
        float w3v = W3[bn * 128 + wn + ni * 16 + lm];
        #pragma unroll
        for (int mi = 0; mi < 4; ++mi)
            #pragma unroll
            for (int r = 0; r < 4; ++r) {
                float v = acc[mi][ni][r] * invs;
                v = v / (1.0f + __expf(-v));
                lt += v * w3v;
            }
    }
    #pragma unroll
    for (int o = 32; o > 0; o >>= 1) lt += __shfl_down(lt, o);
    float* wsum = (float*)smem;
    if (lane == 0) wsum[wave] = lt;
    __syncthreads();
    if (tid == 0)
        nn_part[bm * 8 + bn] = wsum[0] + wsum[1] + wsum[2] + wsum[3];
}

// ------------------------------------------------- finalize: tiny per-batch epilogue
// out[b] = (sum_a psl[a] + sum_{8 partials} nn_part)/128 + comp@Wcomp
__global__ __launch_bounds__(128) void finalize_kernel(
    const float* __restrict__ psl, const int* __restrict__ numbers,
    const float* __restrict__ nn_part, const float* __restrict__ Wcomp,
    float* __restrict__ out)
{
    int b = blockIdx.x, t = threadIdx.x;
    __shared__ float sh[2];
    __shared__ int cnt4[S_SPEC];
    if (t < S_SPEC) cnt4[t] = 0;
    __syncthreads();
    int a = b * 128 + t;
    float e = psl[a];
    if (t < 8) e += nn_part[b * 8 + t];
    atomicAdd(&cnt4[numbers[a]], 1);
    #pragma unroll
    for (int o = 32; o > 0; o >>= 1) e += __shfl_down(e, o);
    if ((t & 63) == 0) sh[t >> 6] = e;
    __syncthreads();
    if (t == 0) {
        float r = (sh[0] + sh[1]) * (1.0f / 128.0f);
        #pragma unroll
        for (int s = 0; s < S_SPEC; ++s) r += (float)cnt4[s] * Wcomp[s];
        out[b] = r;
    }
}

extern "C" void kernel_launch(void* const* d_in, const int* in_sizes, int n_in,
                              void* d_out, int out_size, void* d_ws, size_t ws_size,
                              hipStream_t stream)
{
    const float* positions = (const float*)d_in[0];
    const float* cells     = (const float*)d_in[1];
    const int*   numbers   = (const int*)d_in[2];
    const int*   ei        = (const int*)d_in[3];
    const float* eo        = (const float*)d_in[4];
    const int*   batch     = (const int*)d_in[5];
    const float* gamma     = (const float*)d_in[6];
    const float* beta      = (const float*)d_in[7];
    const float* W_ps      = (const float*)d_in[8];
    const float* W1        = (const float*)d_in[9];
    const float* W2        = (const float*)d_in[10];
    const float* W3        = (const float*)d_in[11];
    const float* W_comp    = (const float*)d_in[12];
    float* out = (float*)d_out;

    char* ws = (char*)d_ws;
    float4* bucket = (float4*)ws;  ws += (size_t)N_ATOMS * S_SPEC * CAP4 * 16;  // 25.2 MB
    u8*    psn  = (u8*)ws;     ws += (size_t)N_ATOMS * PS_DIM;             // 32 MB
    u8*    h1   = (u8*)ws;     ws += (size_t)N_ATOMS * H1_DIM;             // 8 MB
    u8*    Wt1  = (u8*)ws;     ws += (size_t)H1_DIM * PS_DIM;              // 4 MB
    u8*    Wt2  = (u8*)ws;     ws += (size_t)H1_DIM * H1_DIM;              // 1 MB
    float* psl  = (float*)ws;  ws += (size_t)N_ATOMS * 4;
    int*   cnt  = (int*)ws;    ws += (size_t)N_ATOMS * S_SPEC * 4;         // 128 KB
    float* nn_part = (float*)ws; ws += (size_t)1024 * 4;                   // 4 KB

    hipMemsetAsync(cnt, 0, N_ATOMS * S_SPEC * sizeof(int), stream);

    scatter_kernel<<<E_EDGES / 256, 256, 0, stream>>>(
        positions, cells, numbers, ei, eo, batch, cnt, bucket);

    transpose_convert2<<<dim3(160, 32), 256, 0, stream>>>(W1, Wt1, W2, Wt2);

    accum_ps_kernel<<<N_ATOMS / 4, 256, 0, stream>>>(
        bucket, cnt, gamma, beta, W_ps, psn, psl);

    gemm_f8_kernel<<<dim3(N_ATOMS / 128, H1_DIM / 128), 256, 0, stream>>>(
        psn, Wt1, h1, N_ATOMS, H1_DIM, PS_DIM, 1.0f / 64.0f);
    gemm2_fused_kernel<<<dim3(N_ATOMS / 128, H1_DIM / 128), 256, 0, stream>>>(
        h1, Wt2, W3, nn_part, H1_DIM, H1_DIM, 1.0f / 32.0f);

    finalize_kernel<<<B_BATCH, 128, 0, stream>>>(psl, numbers, nn_part, W_comp, out);
}

// Round 16
// 199.202 us; speedup vs baseline: 1.0538x; 1.0126x over previous
//
#include <hip/hip_runtime.h>
#include <hip/hip_bf16.h>
#include <math.h>

#define N_ATOMS 8192
#define B_BATCH 64
#define E_EDGES 262144
#define S_SPEC 4
#define NMAX 8
#define PS_DIM 4096
#define H1_DIM 1024
#define CAP4 48
#define CUTR 5.0f
#define PI_F 3.14159265358979f

typedef __bf16 bf16;
typedef bf16 bf16x8 __attribute__((ext_vector_type(8)));
typedef float floatx4 __attribute__((ext_vector_type(4)));
typedef int intx8 __attribute__((ext_vector_type(8)));
typedef unsigned char u8;

// async global->LDS, 16B per lane; LDS dest = wave-uniform base + lane*16
__device__ __forceinline__ void g2lds16(const void* g, void* l) {
    __builtin_amdgcn_global_load_lds(
        (const __attribute__((address_space(1))) void*)g,
        (__attribute__((address_space(3))) void*)l, 16, 0, 0);
}

__device__ __forceinline__ int pk_fp8x4(float a, float b, float c, float d) {
    int lo = __builtin_amdgcn_cvt_pk_fp8_f32(a, b, 0, false);
    return __builtin_amdgcn_cvt_pk_fp8_f32(c, d, lo, true);
}

// ---------------------------------------------------------------- scatter
__global__ __launch_bounds__(256) void scatter_kernel(
    const float* __restrict__ pos, const float* __restrict__ cells,
    const int* __restrict__ numbers, const int* __restrict__ ei,
    const float* __restrict__ eo, const int* __restrict__ batch,
    int* __restrict__ cnt, float4* __restrict__ bucket)
{
    int e = blockIdx.x * 256 + threadIdx.x;
    int i = ei[e];
    int j = ei[E_EDGES + e];
    int b = batch[i];
    const float* cell = cells + b * 9;
    float o0 = eo[e * 3 + 0], o1 = eo[e * 3 + 1], o2 = eo[e * 3 + 2];
    float rv[3];
    #pragma unroll
    for (int d = 0; d < 3; ++d) {
        float shift = o0 * cell[0 * 3 + d] + o1 * cell[1 * 3 + d] + o2 * cell[2 * 3 + d];
        rv[d] = pos[j * 3 + d] - pos[i * 3 + d] + shift;
    }
    float r2 = rv[0] * rv[0] + rv[1] * rv[1] + rv[2] * rv[2] + 1e-12f;
    if (r2 >= CUTR * CUTR) return;   // fc == 0 -> zero contribution
    float r = sqrtf(r2);
    float a1 = r * (PI_F / CUTR);
    int sp = numbers[j];
    int q = i * S_SPEC + sp;
    int slot = atomicAdd(&cnt[q], 1);
    if (slot < CAP4)
        bucket[q * CAP4 + slot] = make_float4(rv[0], rv[1], rv[2], a1);
}

// ------------------------------------------------- fp32 -> fp8 transposes (both weights)
__global__ __launch_bounds__(256) void transpose_convert2(
    const float* __restrict__ W1, u8* __restrict__ Wt1,
    const float* __restrict__ W2, u8* __restrict__ Wt2)
{
    const float* W; u8* Wt; int K; float scale; int bx;
    if (blockIdx.x < 128) { W = W1; Wt = Wt1; K = PS_DIM; scale = 64.0f; bx = blockIdx.x; }
    else                  { W = W2; Wt = Wt2; K = H1_DIM; scale = 32.0f; bx = blockIdx.x - 128; }
    const int Nc = H1_DIM;
    __shared__ float t[32][33];
    int k0 = bx * 32, n0 = blockIdx.y * 32;
    int tx = threadIdx.x & 31, ty = threadIdx.x >> 5;  // ty in [0,8)
    #pragma unroll
    for (int r = 0; r < 32; r += 8)
        t[ty + r][tx] = W[(size_t)(k0 + ty + r) * Nc + n0 + tx];
    __syncthreads();
    if (threadIdx.x < 64) {
        int nl = threadIdx.x >> 1, cc = threadIdx.x & 1;
        int n = n0 + nl;
        unsigned int w[4];
        #pragma unroll
        for (int g = 0; g < 4; ++g) {
            int kb = cc * 16 + g * 4;
            w[g] = (unsigned int)pk_fp8x4(
                t[kb + 0][nl] * scale, t[kb + 1][nl] * scale,
                t[kb + 2][nl] * scale, t[kb + 3][nl] * scale);
        }
        int gc = (k0 >> 4) + cc;                        // global 16B-chunk index
        int gcs = (gc & ~7) | ((gc & 7) ^ (n & 7));     // swizzled
        *(uint4*)(Wt + (size_t)n * K + (size_t)gcs * 16) = make_uint4(w[0], w[1], w[2], w[3]);
    }
}

// ---------------------------------------------------------------- fused accum + PS/LN
__global__ __launch_bounds__(256) void accum_ps_kernel(
    const float4* __restrict__ bucket, const int* __restrict__ cnt,
    const float* __restrict__ gamma, const float* __restrict__ beta,
    const float* __restrict__ Wps, u8* __restrict__ psn, float* __restrict__ psl)
{
    __shared__ __align__(16) float cl[4][32 * 20];   // [atom][x*20+m], ld=20
    __shared__ __align__(16) u8 ps_s8[PS_DIM];
    __shared__ float red[8];
    __shared__ float red2[4];

    int t = threadIdx.x;
    int wv = t >> 6, lane = t & 63;
    int atom0 = blockIdx.x * 4;

    // ---------------- Phase A ----------------
    {
        int atom = atom0 + wv;
        int sp_l = lane >> 4;
        int nidx = (lane >> 1) & 7;
        float nf = (float)(nidx + 1);
        int par = lane & 1;

        int myCnt = cnt[atom * S_SPEC + sp_l];
        if (myCnt > CAP4) myCnt = CAP4;
        int m1 = max(myCnt, __shfl_xor(myCnt, 16));
        int mx = max(m1, __shfl_xor(m1, 32));

        const float4* q = bucket + (size_t)(atom * S_SPEC + sp_l) * CAP4;
        float acc[8] = {};
        #pragma unroll 2
        for (int e = 0; e < mx; ++e) {
            float4 d = q[e];
            bool valid = e < myCnt;
            float a1 = d.w;
            float inv_r = (PI_F / CUTR) * __frcp_rn(a1);
            float fc = 0.5f * __cosf(a1) + 0.5f;
            float rn = fc * inv_r * __sinf(nf * a1);
            rn = valid ? rn : 0.0f;

            float x = d.x * inv_r, y = d.y * inv_r, z = d.z * inv_r;
            float x2 = x * x, y2 = y * y, z2 = z * z;
            float Ys[8];
            if (par == 0) {
                Ys[0] = 0.28209479f;
                Ys[1] = 0.48860251f * y;
                Ys[2] = 0.48860251f * z;
                Ys[3] = 0.48860251f * x;
                Ys[4] = 1.09254843f * x * y;
                Ys[5] = 1.09254843f * y * z;
                Ys[6] = 0.31539157f * (3.0f * z2 - 1.0f);
                Ys[7] = 1.09254843f * x * z;
            } else {
                Ys[0] = 0.54627422f * (x2 - y2);
                Ys[1] = 0.59004359f * y * (3.0f * x2 - y2);
                Ys[2] = 2.89061144f * x * y * z;
                Ys[3] = 0.45704579f * y * (5.0f * z2 - 1.0f);
                Ys[4] = 0.37317633f * z * (5.0f * z2 - 3.0f);
                Ys[5] = 0.45704579f * x * (5.0f * z2 - 1.0f);
                Ys[6] = 1.44530572f * z * (x2 - y2);
                Ys[7] = 0.59004359f * x * (x2 - 3.0f * y2);
            }
            #pragma unroll
            for (int k = 0; k < 8; ++k) acc[k] += rn * Ys[k];
        }
        int X = sp_l * 8 + nidx;
        float* dst = &cl[wv][X * 20 + par * 8];
        *(float4*)(dst + 0) = make_float4(acc[0], acc[1], acc[2], acc[3]);
        *(float4*)(dst + 4) = make_float4(acc[4], acc[5], acc[6], acc[7]);
    }
    __syncthreads();

    // ---------------- Phase B ----------------
    for (int a = 0; a < 4; ++a) {
        int atom = atom0 + a;
        const float* cl_x = cl[a];

        int y = t & 31;
        int xb = t >> 5;
        float4 cya = *(const float4*)&cl_x[y * 20 + 0];
        float4 cyb = *(const float4*)&cl_x[y * 20 + 4];
        float4 cyc = *(const float4*)&cl_x[y * 20 + 8];
        float4 cyd = *(const float4*)&cl_x[y * 20 + 12];

        float ps[4][4];
        float sum = 0.0f, sumsq = 0.0f;
        #pragma unroll
        for (int q = 0; q < 4; ++q) {
            int x = xb + 8 * q;
            float4 xa = *(const float4*)&cl_x[x * 20 + 0];
            float4 xbv = *(const float4*)&cl_x[x * 20 + 4];
            float4 xc = *(const float4*)&cl_x[x * 20 + 8];
            float4 xd = *(const float4*)&cl_x[x * 20 + 12];
            float s0 = xa.x * cya.x;
            float s1 = xa.y * cya.y + xa.z * cya.z + xa.w * cya.w;
            float s2 = xbv.x * cyb.x + xbv.y * cyb.y + xbv.z * cyb.z + xbv.w * cyb.w
                     + xc.x * cyc.x;
            float s3 = xc.y * cyc.y + xc.z * cyc.z + xc.w * cyc.w
                     + xd.x * cyd.x + xd.y * cyd.y + xd.z * cyd.z + xd.w * cyd.w;
            ps[q][0] = s0; ps[q][1] = s1; ps[q][2] = s2; ps[q][3] = s3;
            sum += s0 + s1 + s2 + s3;
            sumsq += s0 * s0 + s1 * s1 + s2 * s2 + s3 * s3;
        }
        #pragma unroll
        for (int o = 32; o > 0; o >>= 1) {
            sum += __shfl_down(sum, o);
            sumsq += __shfl_down(sumsq, o);
        }
        if ((t & 63) == 0) { red[wv] = sum; red[4 + wv] = sumsq; }
        __syncthreads();
        float tot = red[0] + red[1] + red[2] + red[3];
        float totsq = red[4] + red[5] + red[6] + red[7];
        float mu = tot * (1.0f / PS_DIM);
        float var = totsq * (1.0f / PS_DIM) - mu * mu;
        float inv = rsqrtf(var + 1e-5f);

        float pacc = 0.0f;
        #pragma unroll
        for (int q = 0; q < 4; ++q) {
            int p = t + 256 * q;
            float4 g = *(const float4*)(gamma + p * 4);
            float4 bt = *(const float4*)(beta + p * 4);
            float4 w = *(const float4*)(Wps + p * 4);
            float v0 = (ps[q][0] - mu) * inv * g.x + bt.x;
            float v1 = (ps[q][1] - mu) * inv * g.y + bt.y;
            float v2 = (ps[q][2] - mu) * inv * g.z + bt.z;
            float v3 = (ps[q][3] - mu) * inv * g.w + bt.w;
            pacc += v0 * w.x + v1 * w.y + v2 * w.z + v3 * w.w;
            ((int*)ps_s8)[p] = pk_fp8x4(v0, v1, v2, v3);
        }
        __syncthreads();
        u8* rowp = psn + (size_t)atom * PS_DIM;
        int key = atom & 7;
        int gcs = (t & ~7) | ((t & 7) ^ key);
        *(uint4*)(rowp + (size_t)gcs * 16) = *(const uint4*)(ps_s8 + (size_t)t * 16);

        #pragma unroll
        for (int o = 32; o > 0; o >>= 1) pacc += __shfl_down(pacc, o);
        if ((t & 63) == 0) red2[wv] = pacc;
        __syncthreads();
        if (t == 0) psl[atom] = red2[0] + red2[1] + red2[2] + red2[3];
    }
}

// ------------------------------------------------- MX-fp8 MFMA GEMM1: h1 = fp8(silu(invs*psn@Wt1^T))
// 128x128 block tile (64x64 per wave), BK=256 (two 128B k-subsegments per
// barrier -> 16 barriers instead of 32; occupancy unchanged at 2 blocks/CU
// since LDS 64KB caps at 160/64=2). Swizzle is per-128B-segment, so verbatim
// 256B-row staging preserves it; frag reads add h*128 per k-sub.
__global__ __launch_bounds__(256) void gemm_f8_kernel(
    const u8* __restrict__ A, const u8* __restrict__ Bt,
    u8* __restrict__ H, int M, int Nc, int K, float invs)
{
    __shared__ __align__(16) char smem[65536];   // A: 128x256B = 32KB | B: 128x256B = 32KB
    int tid = threadIdx.x;
    int bm = blockIdx.x, bn = blockIdx.y;
    int wave = tid >> 6, lane = tid & 63;
    int wm = (wave >> 1) * 64, wn = (wave & 1) * 64;
    int lm = lane & 15, quad = lane >> 4;

    floatx4 acc[4][4] = {};
    const int rowA0 = bm * 128, rowB0 = bn * 128;
    const size_t stride = (size_t)K;
    const char* Ab = (const char*)A + (size_t)rowA0 * stride;
    const char* Bb = (const char*)Bt + (size_t)rowB0 * stride;
    const int sA = 0x7F7F7F7F, sB = 0x7F7F7F7F;

    for (int k0 = 0; k0 < K; k0 += 256) {
        #pragma unroll
        for (int s = 0; s < 8; ++s) {      // A: 2048 chunks (16 per 256B row)
            int L = s * 256 + tid;
            int row = L >> 4, boff = (L & 15) * 16;
            int lbase = (s * 256 + wave * 64) * 16;
            g2lds16(Ab + (size_t)row * stride + k0 + boff, smem + lbase);
        }
        #pragma unroll
        for (int s = 0; s < 8; ++s) {      // B: 2048 chunks
            int L = s * 256 + tid;
            int row = L >> 4, boff = (L & 15) * 16;
            int lbase = (s * 256 + wave * 64) * 16;
            g2lds16(Bb + (size_t)row * stride + k0 + boff, smem + 32768 + lbase);
        }
        __syncthreads();
        int key = lm & 7;
        int c0 = (2 * quad) ^ key, c1 = (2 * quad + 1) ^ key;
        #pragma unroll
        for (int h = 0; h < 2; ++h) {      // two 128B k-subsegments per barrier
            intx8 af[4], bfr[4];
            #pragma unroll
            for (int mi = 0; mi < 4; ++mi) {
                const char* base = smem + (wm + mi * 16 + lm) * 256 + h * 128;
                uint4 lo = *(const uint4*)(base + c0 * 16);
                uint4 hi = *(const uint4*)(base + c1 * 16);
                af[mi][0] = lo.x; af[mi][1] = lo.y; af[mi][2] = lo.z; af[mi][3] = lo.w;
                af[mi][4] = hi.x; af[mi][5] = hi.y; af[mi][6] = hi.z; af[mi][7] = hi.w;
            }
            #pragma unroll
            for (int ni = 0; ni < 4; ++ni) {
                const char* base = smem + 32768 + (wn + ni * 16 + lm) * 256 + h * 128;
                uint4 lo = *(const uint4*)(base + c0 * 16);
                uint4 hi = *(const uint4*)(base + c1 * 16);
                bfr[ni][0] = lo.x; bfr[ni][1] = lo.y; bfr[ni][2] = lo.z; bfr[ni][3] = lo.w;
                bfr[ni][4] = hi.x; bfr[ni][5] = hi.y; bfr[ni][6] = hi.z; bfr[ni][7] = hi.w;
            }
            #pragma unroll
            for (int mi = 0; mi < 4; ++mi)
                #pragma unroll
                for (int ni = 0; ni < 4; ++ni)
                    acc[mi][ni] = __builtin_amdgcn_mfma_scale_f32_16x16x128_f8f6f4(
                        af[mi], bfr[ni], acc[mi][ni], 0, 0, 0, sA, 0, sB);
        }
        __syncthreads();
    }

    u8* Cs8 = (u8*)smem;                 // 128 x 128 fp8 = 16KB
    #pragma unroll
    for (int mi = 0; mi < 4; ++mi)
        #pragma unroll
        for (int ni = 0; ni < 4; ++ni)
            #pragma unroll
            for (int r = 0; r < 4; ++r) {
                int row = wm + mi * 16 + quad * 4 + r;
                int col = wn + ni * 16 + lm;
                float v = acc[mi][ni][r] * invs;
                v = v / (1.0f + __expf(-v));
                int pk = __builtin_amdgcn_cvt_pk_fp8_f32(v, 0.0f, 0, false);
                Cs8[row * 128 + col] = (u8)(pk & 0xFF);
            }
    __syncthreads();
    #pragma unroll
    for (int c2 = 0; c2 < 4; ++c2) {
        int L = c2 * 256 + tid;          // 1024 chunks: row = L>>3, cc = L&7
        int row = L >> 3, cc = L & 7;
        int gcs = cc ^ (row & 7);        // rowA0 % 8 == 0
        *(uint4*)(H + (size_t)(rowA0 + row) * Nc + (size_t)(bn * 8 + gcs) * 16) =
            *(const uint4*)(Cs8 + (size_t)L * 16);
    }
}

// ------------------------------------------------- GEMM2 fused with W3 dot
// 128x128 tile, BK=256 (4 barriers for K=1024). Block-scalar plain store to
// nn_part[bm*8+bn]. h2 never touches HBM.
__global__ __launch_bounds__(256) void gemm2_fused_kernel(
    const u8* __restrict__ A, const u8* __restrict__ Bt,
    const float* __restrict__ W3, float* __restrict__ nn_part,
    int Nc, int K, float invs)
{
    __shared__ __align__(16) char smem[65536];
    int tid = threadIdx.x;
    int bm = blockIdx.x, bn = blockIdx.y;
    int wave = tid >> 6, lane = tid & 63;
    int wm = (wave >> 1) * 64, wn = (wave & 1) * 64;
    int lm = lane & 15, quad = lane >> 4;

    floatx4 acc[4][4] = {};
    const int rowA0 = bm * 128, rowB0 = bn * 128;
    const size_t stride = (size_t)K;
    const char* Ab = (const char*)A + (size_t)rowA0 * stride;
    const char* Bb = (const char*)Bt + (size_t)rowB0 * stride;
    const int sA = 0x7F7F7F7F, sB = 0x7F7F7F7F;

    for (int k0 = 0; k0 < K; k0 += 256) {
        #pragma unroll
        for (int s = 0; s < 8; ++s) {
            int L = s * 256 + tid;
            int row = L >> 4, boff = (L & 15) * 16;
            int lbase = (s * 256 + wave * 64) * 16;
            g2lds16(Ab + (size_t)row * stride + k0 + boff, smem + lbase);
        }
        #pragma unroll
        for (int s = 0; s < 8; ++s) {
            int L = s * 256 + tid;
            int row = L >> 4, boff = (L & 15) * 16;
            int lbase = (s * 256 + wave * 64) * 16;
            g2lds16(Bb + (size_t)row * stride + k0 + boff, smem + 32768 + lbase);
        }
        __syncthreads();
        int key = lm & 7;
        int c0 = (2 * quad) ^ key, c1 = (2 * quad + 1) ^ key;
        #pragma unroll
        for (int h = 0; h < 2; ++h) {
            intx8 af[4], bfr[4];
            #pragma unroll
            for (int mi = 0; mi < 4; ++mi) {
                const char* base = smem + (wm + mi * 16 + lm) * 256 + h * 128;
                uint4 lo = *(const uint4*)(base + c0 * 16);
                uint4 hi = *(const uint4*)(base + c1 * 16);
                af[mi][0] = lo.x; af[mi][1] = lo.y; af[mi][2] = lo.z; af[mi][3] = lo.w;
                af[mi][4] = hi.x; af[mi][5] = hi.y; af[mi][6] = hi.z; af[mi][7] = hi.w;
            }
            #pragma unroll
            for (int ni = 0; ni < 4; ++ni) {
                const char* base = smem + 32768 + (wn + ni * 16 + lm) * 256 + h * 128;
                uint4 lo = *(const uint4*)(base + c0 * 16);
                uint4 hi = *(const uint4*)(base + c1 * 16);
                bfr[ni][0] = lo.x; bfr[ni][1] = lo.y; bfr[ni][2] = lo.z; bfr[ni][3] = lo.w;
                bfr[ni][4] = hi.x; bfr[ni][5] = hi.y; bfr[ni][6] = hi.z; bfr[ni][7] = hi.w;
            }
            #pragma unroll
            for (int mi = 0; mi < 4; ++mi)
                #pragma unroll
                for (int ni = 0; ni < 4; ++ni)
                    acc[mi][ni] = __builtin_amdgcn_mfma_scale_f32_16x16x128_f8f6f4(
                        af[mi], bfr[ni], acc[mi][ni], 0, 0, 0, sA, 0, sB);
        }
        __syncthreads();
    }

    // Epilogue: lane-local dot with W3, wave reduce, LDS reduce, ONE plain store.
    float lt = 0.0f;
    #pragma unroll
    for (int ni = 0; ni < 4; ++ni) {
        float w3v = W3[bn * 128 + wn + ni * 16 + lm];
        #pragma unroll
        for (int mi = 0; mi < 4; ++mi)
            #pragma unroll
            for (int r = 0; r < 4; ++r) {
                float v = acc[mi][ni][r] * invs;
                v = v / (1.0f + __expf(-v));
                lt += v * w3v;
            }
    }
    #pragma unroll
    for (int o = 32; o > 0; o >>= 1) lt += __shfl_down(lt, o);
    float* wsum = (float*)smem;
    if (lane == 0) wsum[wave] = lt;
    __syncthreads();
    if (tid == 0)
        nn_part[bm * 8 + bn] = wsum[0] + wsum[1] + wsum[2] + wsum[3];
}

// ------------------------------------------------- finalize: tiny per-batch epilogue
__global__ __launch_bounds__(128) void finalize_kernel(
    const float* __restrict__ psl, const int* __restrict__ numbers,
    const float* __restrict__ nn_part, const float* __restrict__ Wcomp,
    float* __restrict__ out)
{
    int b = blockIdx.x, t = threadIdx.x;
    __shared__ float sh[2];
    __shared__ int cnt4[S_SPEC];
    if (t < S_SPEC) cnt4[t] = 0;
    __syncthreads();
    int a = b * 128 + t;
    float e = psl[a];
    if (t < 8) e += nn_part[b * 8 + t];
    atomicAdd(&cnt4[numbers[a]], 1);
    #pragma unroll
    for (int o = 32; o > 0; o >>= 1) e += __shfl_down(e, o);
    if ((t & 63) == 0) sh[t >> 6] = e;
    __syncthreads();
    if (t == 0) {
        float r = (sh[0] + sh[1]) * (1.0f / 128.0f);
        #pragma unroll
        for (int s = 0; s < S_SPEC; ++s) r += (float)cnt4[s] * Wcomp[s];
        out[b] = r;
    }
}

extern "C" void kernel_launch(void* const* d_in, const int* in_sizes, int n_in,
                              void* d_out, int out_size, void* d_ws, size_t ws_size,
                              hipStream_t stream)
{
    const float* positions = (const float*)d_in[0];
    const float* cells     = (const float*)d_in[1];
    const int*   numbers   = (const int*)d_in[2];
    const int*   ei        = (const int*)d_in[3];
    const float* eo        = (const float*)d_in[4];
    const int*   batch     = (const int*)d_in[5];
    const float* gamma     = (const float*)d_in[6];
    const float* beta      = (const float*)d_in[7];
    const float* W_ps      = (const float*)d_in[8];
    const float* W1        = (const float*)d_in[9];
    const float* W2        = (const float*)d_in[10];
    const float* W3        = (const float*)d_in[11];
    const float* W_comp    = (const float*)d_in[12];
    float* out = (float*)d_out;

    char* ws = (char*)d_ws;
    float4* bucket = (float4*)ws;  ws += (size_t)N_ATOMS * S_SPEC * CAP4 * 16;  // 25.2 MB
    u8*    psn  = (u8*)ws;     ws += (size_t)N_ATOMS * PS_DIM;             // 32 MB
    u8*    h1   = (u8*)ws;     ws += (size_t)N_ATOMS * H1_DIM;             // 8 MB
    u8*    Wt1  = (u8*)ws;     ws += (size_t)H1_DIM * PS_DIM;              // 4 MB
    u8*    Wt2  = (u8*)ws;     ws += (size_t)H1_DIM * H1_DIM;              // 1 MB
    float* psl  = (float*)ws;  ws += (size_t)N_ATOMS * 4;
    int*   cnt  = (int*)ws;    ws += (size_t)N_ATOMS * S_SPEC * 4;         // 128 KB
    float* nn_part = (float*)ws; ws += (size_t)1024 * 4;                   // 4 KB

    hipMemsetAsync(cnt, 0, N_ATOMS * S_SPEC * sizeof(int), stream);

    scatter_kernel<<<E_EDGES / 256, 256, 0, stream>>>(
        positions, cells, numbers, ei, eo, batch, cnt, bucket);

    transpose_convert2<<<dim3(160, 32), 256, 0, stream>>>(W1, Wt1, W2, Wt2);

    accum_ps_kernel<<<N_ATOMS / 4, 256, 0, stream>>>(
        bucket, cnt, gamma, beta, W_ps, psn, psl);

    gemm_f8_kernel<<<dim3(N_ATOMS / 128, H1_DIM / 128), 256, 0, stream>>>(
        psn, Wt1, h1, N_ATOMS, H1_DIM, PS_DIM, 1.0f / 64.0f);
    gemm2_fused_kernel<<<dim3(N_ATOMS / 128, H1_DIM / 128), 256, 0, stream>>>(
        h1, Wt2, W3, nn_part, H1_DIM, H1_DIM, 1.0f / 32.0f);

    finalize_kernel<<<B_BATCH, 128, 0, stream>>>(psl, numbers, nn_part, W_comp, out);
}